// Round 10
// baseline (950.387 us; speedup 1.0000x reference)
//
#include <hip/hip_runtime.h>
#include <hip/hip_bf16.h>

typedef __hip_bfloat16 bf16;

#define ALPHA 0.2f
#define NEGV  -9.0e15f

__device__ __forceinline__ float b2f(bf16 x){ return __bfloat162float(x); }
__device__ __forceinline__ bf16  f2b(float x){ return __float2bfloat16(x); }
__device__ __forceinline__ float lrelu(float x){ return x > 0.f ? x : ALPHA*x; }
__device__ __forceinline__ float eluf(float x){ return x > 0.f ? x : expm1f(x); }

// ---------------- params block offsets (f32 elements) ----------------------
#define P_ATOMS_MASK 0
#define P_AMINO_MASK 8192
#define P_E_ATOM     24576
#define P_E_AMINO    37376
#define P_W_GAT      41216
#define P_A_GAT      73984
#define P_W_GO       74496
#define P_A_GO       107264
#define P_W_COMP_W   107520
#define P_W_COMP_B   123904
#define P_CONV_W     124032
#define P_CONV_B     124395
#define P_W_ATT_W    124398
#define P_W_ATT_B    140782
#define P_PRED_W     140910
#define P_PRED_B     141166
#define P_TOTAL      141167

// ---------------------------------------------------------------------------
// Per-tensor convert to f32 params. Storage dtype detected per tensor:
// f32 storage -> even halfwords are random mantissa bits (implausible bf16
// exponents, P(miss)~1e-28) or the [0x0000,0x3F80,...] all-ones-mask pattern;
// bf16 storage -> head values all plausible. All-zero tensors identical.
__global__ __launch_bounds__(256) void k_cvt(const void* src, float* dst, int n)
{
    __shared__ int mode;
    const unsigned short* u = (const unsigned short*)src;
    if (threadIdx.x == 0) {
        int lim = n < 64 ? n : 64;
        bool f32like = false;
        for (int i = 0; i < lim; i += 2) {
            unsigned short h = u[i];
            int e = (h >> 7) & 0xFF;
            bool z = (h & 0x7FFF) == 0;
            if (!(z || (e >= 0x66 && e <= 0x88))) f32like = true;
        }
        if (!f32like && lim > 1 && (u[0] & 0x7FFF) == 0 && (u[1] & 0x7FFF) != 0)
            f32like = true;                      // f32-stored all-ones mask
        mode = f32like ? 1 : 0;
    }
    __syncthreads();
    int idx = blockIdx.x*256 + threadIdx.x;
    if (idx < n)
        dst[idx] = mode ? ((const float*)src)[idx] : b2f(((const bf16*)src)[idx]);
}

// ---------------------------------------------------------------------------
// GAT layer 1 pre: av = E_atom[atoms]; Wh1 = av @ W_gat[h] (bf16 out); dots.
__global__ __launch_bounds__(256) void k_gat1_pre(
    const int* __restrict__ atoms, const float* __restrict__ params,
    bf16* __restrict__ Wh1, float* __restrict__ src1, float* __restrict__ dst1)
{
    int bid = blockIdx.x;              // b*512 + n
    int b = bid >> 9, n = bid & 511;
    int tid = threadIdx.x;
    __shared__ float av[128];
    if (tid < 128) av[tid] = params[P_E_ATOM + atoms[bid]*128 + tid];
    __syncthreads();
    int h = tid >> 6, f = tid & 63;
    const float* Wp = params + P_W_GAT + h*8192 + f;     // W_gat[h][k][f]
    float wh = 0.f;
    #pragma unroll 8
    for (int k = 0; k < 128; ++k) wh += av[k] * Wp[k*64];
    Wh1[(size_t)bid*256 + h*64 + f] = f2b(wh);
    float p1 = wh * params[P_A_GAT + h*128 + f];
    float p2 = wh * params[P_A_GAT + h*128 + 64 + f];
    #pragma unroll
    for (int m = 32; m; m >>= 1) { p1 += __shfl_xor(p1, m, 64); p2 += __shfl_xor(p2, m, 64); }
    if (f == 0) { src1[(b*4+h)*512 + n] = p1; dst1[(b*4+h)*512 + n] = p2; }
}

// ---------------------------------------------------------------------------
// GAT layer 1 attention: block per (b,h,i). softmax over 512 j, hp=att@Wh, elu.
__global__ __launch_bounds__(256) void k_gat1_att(
    const int* __restrict__ adj, const bf16* __restrict__ Wh1,
    const float* __restrict__ src1, const float* __restrict__ dst1,
    bf16* __restrict__ multi)
{
    int bid = blockIdx.x;
    int i = bid & 511, h = (bid >> 9) & 3, b = bid >> 11;
    int tid = threadIdx.x;
    __shared__ float att[512];
    __shared__ float red[256];
    float s_i = src1[(b*4+h)*512 + i];
    const int* adjrow = adj + ((size_t)(b*512 + i))*512;
    const float* dstp = dst1 + (b*4+h)*512;
    float lm = -3.0e38f;
    for (int j = tid; j < 512; j += 256) {
        float e = lrelu(s_i + dstp[j]);
        e = adjrow[j] > 0 ? e : NEGV;
        att[j] = e;
        lm = fmaxf(lm, e);
    }
    #pragma unroll
    for (int m = 32; m; m >>= 1) lm = fmaxf(lm, __shfl_xor(lm, m, 64));
    if ((tid & 63) == 0) red[tid >> 6] = lm;
    __syncthreads();
    float M = fmaxf(fmaxf(red[0], red[1]), fmaxf(red[2], red[3]));
    float ls = 0.f;
    for (int j = tid; j < 512; j += 256) {
        float ex = __expf(att[j] - M);
        att[j] = ex;
        ls += ex;
    }
    #pragma unroll
    for (int m = 32; m; m >>= 1) ls += __shfl_xor(ls, m, 64);
    if ((tid & 63) == 0) red[4 + (tid >> 6)] = ls;
    __syncthreads();
    float inv = 1.f / (red[4] + red[5] + red[6] + red[7]);
    int f = tid & 63, c = tid >> 6;
    const bf16* Whp = Wh1 + (size_t)(b*512)*256 + h*64 + f;
    float part = 0.f;
    int j0 = c * 128;
    #pragma unroll 4
    for (int j = 0; j < 128; ++j) part += att[j0 + j] * b2f(Whp[(size_t)(j0 + j)*256]);
    __syncthreads();
    red[tid] = part;
    __syncthreads();
    if (c == 0) {
        float hp = (red[f] + red[f+64] + red[f+128] + red[f+192]) * inv;
        multi[(size_t)(b*512 + i)*256 + h*64 + f] = f2b(eluf(hp));
    }
}

// ---------------------------------------------------------------------------
// GAT layer 2 pre: Wh2 = multi @ W_go (256->128), src2/dst2 dots with a_go.
__global__ __launch_bounds__(128) void k_gat2_pre(
    const bf16* __restrict__ multi, const float* __restrict__ params,
    bf16* __restrict__ Wh2, float* __restrict__ src2, float* __restrict__ dst2)
{
    int bid = blockIdx.x;              // b*512 + n
    int tid = threadIdx.x;
    __shared__ float row[256];
    __shared__ float sr[2][2];
    row[tid]       = b2f(multi[(size_t)bid*256 + tid]);
    row[tid + 128] = b2f(multi[(size_t)bid*256 + tid + 128]);
    __syncthreads();
    const float* Wp = params + P_W_GO;
    float wh = 0.f;
    #pragma unroll 8
    for (int k = 0; k < 256; ++k) wh += row[k] * Wp[k*128 + tid];
    Wh2[(size_t)bid*128 + tid] = f2b(wh);
    float p1 = wh * params[P_A_GO + tid];
    float p2 = wh * params[P_A_GO + 128 + tid];
    #pragma unroll
    for (int m = 32; m; m >>= 1) { p1 += __shfl_xor(p1, m, 64); p2 += __shfl_xor(p2, m, 64); }
    int wid = tid >> 6;
    if ((tid & 63) == 0) { sr[0][wid] = p1; sr[1][wid] = p2; }
    __syncthreads();
    if (tid == 0) src2[bid] = sr[0][0] + sr[0][1];
    if (tid == 1) dst2[bid] = sr[1][0] + sr[1][1];
}

// ---------------------------------------------------------------------------
// GAT layer 2 attention: block per (b,i). F=128. x = elu(att@Wh2).
__global__ __launch_bounds__(256) void k_gat2_att(
    const int* __restrict__ adj, const bf16* __restrict__ Wh2,
    const float* __restrict__ src2, const float* __restrict__ dst2,
    bf16* __restrict__ x)
{
    int bid = blockIdx.x;              // b*512 + i
    int b = bid >> 9;
    int tid = threadIdx.x;
    __shared__ float att[512];
    __shared__ float red[256];
    float s_i = src2[bid];
    const int* adjrow = adj + (size_t)bid*512;
    const float* dstp = dst2 + b*512;
    float lm = -3.0e38f;
    for (int j = tid; j < 512; j += 256) {
        float e = lrelu(s_i + dstp[j]);
        e = adjrow[j] > 0 ? e : NEGV;
        att[j] = e;
        lm = fmaxf(lm, e);
    }
    #pragma unroll
    for (int m = 32; m; m >>= 1) lm = fmaxf(lm, __shfl_xor(lm, m, 64));
    if ((tid & 63) == 0) red[tid >> 6] = lm;
    __syncthreads();
    float M = fmaxf(fmaxf(red[0], red[1]), fmaxf(red[2], red[3]));
    float ls = 0.f;
    for (int j = tid; j < 512; j += 256) {
        float ex = __expf(att[j] - M);
        att[j] = ex;
        ls += ex;
    }
    #pragma unroll
    for (int m = 32; m; m >>= 1) ls += __shfl_xor(ls, m, 64);
    if ((tid & 63) == 0) red[4 + (tid >> 6)] = ls;
    __syncthreads();
    float inv = 1.f / (red[4] + red[5] + red[6] + red[7]);
    int f = tid & 127, c = tid >> 7;
    const bf16* Whp = Wh2 + (size_t)(b*512)*128 + f;
    float part = 0.f;
    int j0 = c * 256;
    #pragma unroll 4
    for (int j = 0; j < 256; ++j) part += att[j0 + j] * b2f(Whp[(size_t)(j0 + j)*128]);
    __syncthreads();
    red[tid] = part;
    __syncthreads();
    if (c == 0) {
        float hp = (red[f] + red[f+128]) * inv;
        x[(size_t)bid*128 + f] = f2b(eluf(hp));
    }
}

// ---------------------------------------------------------------------------
// atoms_vec[row,l] = leaky(x[row,:] . W_comp[l,:] + b[l])
__global__ __launch_bounds__(128) void k_rowmat_leaky(
    const bf16* __restrict__ in, const float* __restrict__ params,
    bf16* __restrict__ out)
{
    int bid = blockIdx.x;
    int tid = threadIdx.x;
    __shared__ float row[128];
    row[tid] = b2f(in[(size_t)bid*128 + tid]);
    __syncthreads();
    const float* W = params + P_W_COMP_W;
    float v = 0.f;
    #pragma unroll 8
    for (int k = 0; k < 128; ++k) v += row[k] * W[tid*128 + k];
    v = lrelu(v + params[P_W_COMP_B + tid]);
    out[(size_t)bid*128 + tid] = f2b(v);
}

// ---------------------------------------------------------------------------
// v = leaky(in[row,:] . W_att[l,:] + b[l]) * mask[row]; atomic acc per (b,l).
__global__ __launch_bounds__(128) void k_att_acc(
    const bf16* __restrict__ in, const float* __restrict__ params,
    const float* __restrict__ mask, float* __restrict__ acc, int per_b)
{
    int bid = blockIdx.x;
    int b = bid / per_b;
    int tid = threadIdx.x;
    __shared__ float row[128];
    row[tid] = b2f(in[(size_t)bid*128 + tid]);
    __syncthreads();
    const float* W = params + P_W_ATT_W;
    float v = 0.f;
    #pragma unroll 8
    for (int k = 0; k < 128; ++k) v += row[k] * W[tid*128 + k];
    v = lrelu(v + params[P_W_ATT_B + tid]);
    v *= mask[bid];
    atomicAdd(&acc[b*128 + tid], v);
}

// ---------------------------------------------------------------------------
// 11x11 SAME conv over (1024,128) + relu. layer 0 gathers E_amino from params.
__global__ __launch_bounds__(128) void k_conv(
    const bf16* __restrict__ in, const int* __restrict__ amino,
    const float* __restrict__ params, bf16* __restrict__ out,
    int layer, int first)
{
    int bid = blockIdx.x;              // b*1024 + i
    int b = bid >> 10, i = bid & 1023;
    int tid = threadIdx.x;
    __shared__ float tile[11][139];
    __shared__ float wts[121];
    __shared__ float bias;
    if (tid < 121) wts[tid] = params[P_CONV_W + layer*121 + tid];
    if (tid == 121) bias = params[P_CONV_B + layer];
    for (int idx = tid; idx < 11*138; idx += 128) {
        int r = idx / 138, cc = idx % 138;
        int ri = i + r - 5, cj = cc - 5;
        float v = 0.f;
        if (ri >= 0 && ri < 1024 && cj >= 0 && cj < 128) {
            v = first ? params[P_E_AMINO + amino[b*1024 + ri]*128 + cj]
                      : b2f(in[((size_t)(b*1024 + ri))*128 + cj]);
        }
        tile[r][cc] = v;
    }
    __syncthreads();
    float a = bias;
    #pragma unroll
    for (int di = 0; di < 11; ++di)
        #pragma unroll
        for (int dj = 0; dj < 11; ++dj)
            a += tile[di][tid + dj] * wts[di*11 + dj];
    out[(size_t)bid*128 + tid] = f2b(fmaxf(a, 0.f));
}

// ---------------------------------------------------------------------------
// final: mask means, leaky x2, pred dot.  block per b.  OUTPUT IS FLOAT32.
__global__ __launch_bounds__(256) void k_final(
    const float* __restrict__ params, const float* __restrict__ acc,
    float* __restrict__ out)
{
    int b = blockIdx.x, tid = threadIdx.x;
    __shared__ float red[256];
    float s = 0.f;
    for (int t = tid; t < 512; t += 256) s += params[P_ATOMS_MASK + b*512 + t];
    #pragma unroll
    for (int m = 32; m; m >>= 1) s += __shfl_xor(s, m, 64);
    if ((tid & 63) == 0) red[tid >> 6] = s;
    __syncthreads();
    float sum_atoms = red[0]+red[1]+red[2]+red[3];
    __syncthreads();
    s = 0.f;
    for (int t = tid; t < 1024; t += 256) s += params[P_AMINO_MASK + b*1024 + t];
    #pragma unroll
    for (int m = 32; m; m >>= 1) s += __shfl_xor(s, m, 64);
    if ((tid & 63) == 0) red[tid >> 6] = s;
    __syncthreads();
    float sum_amino = red[0]+red[1]+red[2]+red[3];
    __syncthreads();
    float val = (tid < 128) ? acc[b*128 + tid] / sum_atoms
                            : acc[2048 + b*128 + (tid-128)] / sum_amino;
    val = lrelu(lrelu(val));
    val *= params[P_PRED_W + tid];
    #pragma unroll
    for (int m = 32; m; m >>= 1) val += __shfl_xor(val, m, 64);
    if ((tid & 63) == 0) red[tid >> 6] = val;
    __syncthreads();
    if (tid == 0) out[b] = red[0]+red[1]+red[2]+red[3] + params[P_PRED_B];
}

// ---------------------------------------------------------------------------
extern "C" void kernel_launch(void* const* d_in, const int* in_sizes, int n_in,
                              void* d_out, int out_size, void* d_ws, size_t ws_size,
                              hipStream_t stream)
{
    const int* atoms     = (const int*)d_in[0];
    const int* adjacency = (const int*)d_in[2];
    const int* amino     = (const int*)d_in[3];
    float* out = (float*)d_out;                  // reference output dtype = f32
    (void)in_sizes; (void)n_in; (void)ws_size;

    // ws layout: total ~12.9 MiB
    char* base = (char*)d_ws;
    float* params = (float*)(base + 0);          // 141167 f32 (565 KB)
    float* src1   = (float*)(base + 565248);     // 32768 f32
    float* dst1   = (float*)(base + 696320);     // 32768 f32
    float* src2   = (float*)(base + 827392);     // 8192 f32
    float* dst2   = (float*)(base + 860160);     // 8192 f32
    float* acc    = (float*)(base + 892928);     // 4096 f32 (comp | prot)
    bf16*  A      = (bf16*)(base + 909568);      // 2,097,152 bf16
    bf16*  B      = (bf16*)(base + 5103872);     // 2,097,152 bf16
    bf16*  C      = (bf16*)(base + 9298176);     // 2,097,152 bf16

    bf16* Wh1 = B;
    bf16* multi = C;
    bf16* Wh2 = B;                 // first 1,048,576 elems (Wh1 dead)
    bf16* xbuf = B + 1048576;      // second 1,048,576 elems
    bf16* atoms_vec = C;           // multi dead

    hipMemsetAsync(acc, 0, 4096*sizeof(float), stream);

    // per-tensor conversions (small kernargs)
    k_cvt<<< 32, 256, 0, stream>>>(d_in[1],  params + P_ATOMS_MASK, 8192);
    k_cvt<<< 64, 256, 0, stream>>>(d_in[4],  params + P_AMINO_MASK, 16384);
    k_cvt<<< 50, 256, 0, stream>>>(d_in[5],  params + P_E_ATOM,     12800);
    k_cvt<<< 15, 256, 0, stream>>>(d_in[6],  params + P_E_AMINO,    3840);
    k_cvt<<<128, 256, 0, stream>>>(d_in[7],  params + P_W_GAT,      32768);
    k_cvt<<<  2, 256, 0, stream>>>(d_in[8],  params + P_A_GAT,      512);
    k_cvt<<<128, 256, 0, stream>>>(d_in[9],  params + P_W_GO,       32768);
    k_cvt<<<  1, 256, 0, stream>>>(d_in[10], params + P_A_GO,       256);
    k_cvt<<< 64, 256, 0, stream>>>(d_in[11], params + P_W_COMP_W,   16384);
    k_cvt<<<  1, 256, 0, stream>>>(d_in[12], params + P_W_COMP_B,   128);
    k_cvt<<<  2, 256, 0, stream>>>(d_in[13], params + P_CONV_W,     363);
    k_cvt<<<  1, 256, 0, stream>>>(d_in[14], params + P_CONV_B,     3);
    k_cvt<<< 64, 256, 0, stream>>>(d_in[15], params + P_W_ATT_W,    16384);
    k_cvt<<<  1, 256, 0, stream>>>(d_in[16], params + P_W_ATT_B,    128);
    k_cvt<<<  1, 256, 0, stream>>>(d_in[17], params + P_PRED_W,     256);
    k_cvt<<<  1, 256, 0, stream>>>(d_in[18], params + P_PRED_B,     1);

    // protein conv chain
    k_conv<<<16384, 128, 0, stream>>>(nullptr, amino, params, A, 0, 1);
    k_conv<<<16384, 128, 0, stream>>>(A,       amino, params, B, 1, 0);
    k_conv<<<16384, 128, 0, stream>>>(B,       amino, params, A, 2, 0);   // A = amino_vec

    // GAT layer 1 (4 heads)
    k_gat1_pre<<<8192, 256, 0, stream>>>(atoms, params, Wh1, src1, dst1);
    k_gat1_att<<<32768, 256, 0, stream>>>(adjacency, Wh1, src1, dst1, multi);

    // GAT layer 2
    k_gat2_pre<<<8192, 128, 0, stream>>>(multi, params, Wh2, src2, dst2);
    k_gat2_att<<<8192, 256, 0, stream>>>(adjacency, Wh2, src2, dst2, xbuf);

    // atoms_vec = leaky(x @ W_comp^T + b)
    k_rowmat_leaky<<<8192, 128, 0, stream>>>(xbuf, params, atoms_vec);

    // masked attention-pool accumulations
    k_att_acc<<<8192, 128, 0, stream>>>(atoms_vec, params, params + P_ATOMS_MASK, acc, 512);
    k_att_acc<<<16384, 128, 0, stream>>>(A, params, params + P_AMINO_MASK, acc + 2048, 1024);

    // head (float32 output)
    k_final<<<16, 256, 0, stream>>>(params, acc, out);
}

// Round 11
// 600.744 us; speedup vs baseline: 1.5820x; 1.5820x over previous
//
#include <hip/hip_runtime.h>
#include <hip/hip_bf16.h>

typedef __hip_bfloat16 bf16;

#define ALPHA 0.2f
#define NEGV  -9.0e15f

__device__ __forceinline__ float b2f(bf16 x){ return __bfloat162float(x); }
__device__ __forceinline__ bf16  f2b(float x){ return __float2bfloat16(x); }
__device__ __forceinline__ float lrelu(float x){ return x > 0.f ? x : ALPHA*x; }
__device__ __forceinline__ float eluf(float x){ return x > 0.f ? x : expm1f(x); }

// ---------------- params block offsets (f32 elements) ----------------------
#define P_ATOMS_MASK 0
#define P_AMINO_MASK 8192
#define P_E_ATOM     24576
#define P_E_AMINO    37376
#define P_W_GAT      41216
#define P_A_GAT      73984
#define P_W_GO       74496
#define P_A_GO       107264
#define P_W_COMP_W   107520
#define P_W_COMP_B   123904
#define P_CONV_W     124032
#define P_CONV_B     124395
#define P_W_ATT_W    124398
#define P_W_ATT_B    140782
#define P_PRED_W     140910
#define P_PRED_B     141166
#define P_TOTAL      141167

// ---------------------------------------------------------------------------
// Per-tensor convert to f32 params (storage dtype auto-detected per tensor).
__global__ __launch_bounds__(256) void k_cvt(const void* src, float* dst, int n)
{
    __shared__ int mode;
    const unsigned short* u = (const unsigned short*)src;
    if (threadIdx.x == 0) {
        int lim = n < 64 ? n : 64;
        bool f32like = false;
        for (int i = 0; i < lim; i += 2) {
            unsigned short h = u[i];
            int e = (h >> 7) & 0xFF;
            bool z = (h & 0x7FFF) == 0;
            if (!(z || (e >= 0x66 && e <= 0x88))) f32like = true;
        }
        if (!f32like && lim > 1 && (u[0] & 0x7FFF) == 0 && (u[1] & 0x7FFF) != 0)
            f32like = true;                      // f32-stored all-ones mask
        mode = f32like ? 1 : 0;
    }
    __syncthreads();
    int idx = blockIdx.x*256 + threadIdx.x;
    if (idx < n)
        dst[idx] = mode ? ((const float*)src)[idx] : b2f(((const bf16*)src)[idx]);
}

// ---------------------------------------------------------------------------
// GAT layer 1 pre: av = E_atom[atoms]; Wh1 = av @ W_gat[h] (bf16 out); dots.
__global__ __launch_bounds__(256) void k_gat1_pre(
    const int* __restrict__ atoms, const float* __restrict__ params,
    bf16* __restrict__ Wh1, float* __restrict__ src1, float* __restrict__ dst1)
{
    int bid = blockIdx.x;              // b*512 + n
    int b = bid >> 9, n = bid & 511;
    int tid = threadIdx.x;
    __shared__ float av[128];
    if (tid < 128) av[tid] = params[P_E_ATOM + atoms[bid]*128 + tid];
    __syncthreads();
    int h = tid >> 6, f = tid & 63;
    const float* Wp = params + P_W_GAT + h*8192 + f;     // W_gat[h][k][f]
    float wh = 0.f;
    #pragma unroll 8
    for (int k = 0; k < 128; ++k) wh += av[k] * Wp[k*64];
    Wh1[(size_t)bid*256 + h*64 + f] = f2b(wh);
    float p1 = wh * params[P_A_GAT + h*128 + f];
    float p2 = wh * params[P_A_GAT + h*128 + 64 + f];
    #pragma unroll
    for (int m = 32; m; m >>= 1) { p1 += __shfl_xor(p1, m, 64); p2 += __shfl_xor(p2, m, 64); }
    if (f == 0) { src1[(b*4+h)*512 + n] = p1; dst1[(b*4+h)*512 + n] = p2; }
}

// ---------------------------------------------------------------------------
// GAT layer 1 attention, ALL 4 HEADS per block. block = (b,i), wave h = head h.
// Per-wave softmax over 512 in register/LDS; ILP-4 matvec att@Wh.
__global__ __launch_bounds__(256) void k_gat1_att4(
    const int* __restrict__ adj, const bf16* __restrict__ Wh1,
    const float* __restrict__ src1, const float* __restrict__ dst1,
    bf16* __restrict__ multi)
{
    int bid = blockIdx.x;              // b*512 + i
    int b = bid >> 9, i = bid & 511;
    int tid = threadIdx.x;
    int h = tid >> 6, lane = tid & 63;
    __shared__ float att[4][512];
    const int* adjrow = adj + (size_t)bid*512;
    const float* dstp = dst1 + (b*4+h)*512;
    float s_i = src1[(b*4+h)*512 + i];
    float lm = -3.0e38f;
    #pragma unroll
    for (int jj = 0; jj < 8; ++jj) {
        int j = lane + jj*64;
        float e = lrelu(s_i + dstp[j]);
        e = adjrow[j] > 0 ? e : NEGV;
        att[h][j] = e;
        lm = fmaxf(lm, e);
    }
    #pragma unroll
    for (int m = 32; m; m >>= 1) lm = fmaxf(lm, __shfl_xor(lm, m, 64));
    float ls = 0.f;
    #pragma unroll
    for (int jj = 0; jj < 8; ++jj) {
        int j = lane + jj*64;
        float ex = __expf(att[h][j] - lm);
        att[h][j] = ex;
        ls += ex;
    }
    #pragma unroll
    for (int m = 32; m; m >>= 1) ls += __shfl_xor(ls, m, 64);
    float inv = 1.f / ls;
    // matvec: wave h owns att[h] (wave-coherent LDS, no block sync needed)
    const bf16* Whp = Wh1 + (size_t)(b*512)*256 + h*64 + lane;
    float a0=0.f, a1=0.f, a2=0.f, a3=0.f;
    for (int j = 0; j < 512; j += 4) {
        a0 += att[h][j]   * b2f(Whp[(size_t)(j)*256]);
        a1 += att[h][j+1] * b2f(Whp[(size_t)(j+1)*256]);
        a2 += att[h][j+2] * b2f(Whp[(size_t)(j+2)*256]);
        a3 += att[h][j+3] * b2f(Whp[(size_t)(j+3)*256]);
    }
    float hp = (a0+a1+a2+a3) * inv;
    multi[(size_t)bid*256 + h*64 + lane] = f2b(eluf(hp));
}

// ---------------------------------------------------------------------------
// GAT layer 2 pre: Wh2 = multi @ W_go (256->128), src2/dst2 dots with a_go.
__global__ __launch_bounds__(128) void k_gat2_pre(
    const bf16* __restrict__ multi, const float* __restrict__ params,
    bf16* __restrict__ Wh2, float* __restrict__ src2, float* __restrict__ dst2)
{
    int bid = blockIdx.x;              // b*512 + n
    int tid = threadIdx.x;
    __shared__ float row[256];
    __shared__ float sr[2][2];
    row[tid]       = b2f(multi[(size_t)bid*256 + tid]);
    row[tid + 128] = b2f(multi[(size_t)bid*256 + tid + 128]);
    __syncthreads();
    const float* Wp = params + P_W_GO;
    float wh = 0.f;
    #pragma unroll 8
    for (int k = 0; k < 256; ++k) wh += row[k] * Wp[k*128 + tid];
    Wh2[(size_t)bid*128 + tid] = f2b(wh);
    float p1 = wh * params[P_A_GO + tid];
    float p2 = wh * params[P_A_GO + 128 + tid];
    #pragma unroll
    for (int m = 32; m; m >>= 1) { p1 += __shfl_xor(p1, m, 64); p2 += __shfl_xor(p2, m, 64); }
    int wid = tid >> 6;
    if ((tid & 63) == 0) { sr[0][wid] = p1; sr[1][wid] = p2; }
    __syncthreads();
    if (tid == 0) src2[bid] = sr[0][0] + sr[0][1];
    if (tid == 1) dst2[bid] = sr[1][0] + sr[1][1];
}

// ---------------------------------------------------------------------------
// GAT layer 2 attention: block per (b,i). F=128. x = elu(att@Wh2). ILP-4.
__global__ __launch_bounds__(256) void k_gat2_att(
    const int* __restrict__ adj, const bf16* __restrict__ Wh2,
    const float* __restrict__ src2, const float* __restrict__ dst2,
    bf16* __restrict__ x)
{
    int bid = blockIdx.x;              // b*512 + i
    int b = bid >> 9;
    int tid = threadIdx.x;
    __shared__ float att[512];
    __shared__ float red[256];
    float s_i = src2[bid];
    const int* adjrow = adj + (size_t)bid*512;
    const float* dstp = dst2 + b*512;
    float lm = -3.0e38f;
    for (int j = tid; j < 512; j += 256) {
        float e = lrelu(s_i + dstp[j]);
        e = adjrow[j] > 0 ? e : NEGV;
        att[j] = e;
        lm = fmaxf(lm, e);
    }
    #pragma unroll
    for (int m = 32; m; m >>= 1) lm = fmaxf(lm, __shfl_xor(lm, m, 64));
    if ((tid & 63) == 0) red[tid >> 6] = lm;
    __syncthreads();
    float M = fmaxf(fmaxf(red[0], red[1]), fmaxf(red[2], red[3]));
    float ls = 0.f;
    for (int j = tid; j < 512; j += 256) {
        float ex = __expf(att[j] - M);
        att[j] = ex;
        ls += ex;
    }
    #pragma unroll
    for (int m = 32; m; m >>= 1) ls += __shfl_xor(ls, m, 64);
    if ((tid & 63) == 0) red[4 + (tid >> 6)] = ls;
    __syncthreads();
    float inv = 1.f / (red[4] + red[5] + red[6] + red[7]);
    int f = tid & 127, c = tid >> 7;
    const bf16* Whp = Wh2 + (size_t)(b*512)*128 + f;
    int j0 = c * 256;
    float a0=0.f, a1=0.f, a2=0.f, a3=0.f;
    for (int j = 0; j < 256; j += 4) {
        a0 += att[j0+j]   * b2f(Whp[(size_t)(j0+j)*128]);
        a1 += att[j0+j+1] * b2f(Whp[(size_t)(j0+j+1)*128]);
        a2 += att[j0+j+2] * b2f(Whp[(size_t)(j0+j+2)*128]);
        a3 += att[j0+j+3] * b2f(Whp[(size_t)(j0+j+3)*128]);
    }
    float part = (a0+a1) + (a2+a3);
    __syncthreads();
    red[tid] = part;
    __syncthreads();
    if (c == 0) {
        float hp = (red[f] + red[f+128]) * inv;
        x[(size_t)bid*128 + f] = f2b(eluf(hp));
    }
}

// ---------------------------------------------------------------------------
// Tiled row-matvec: out[r][l] = lrelu(in[r][:] . W[l][:] + bias[l]).
// W (128x128 f32, row-major [l][k]) staged in LDS padded to 129 (conflict-free);
// 32 rows per block; 4-row ILP per thread. 256 threads: l = tid&127, g = tid>>7.
#define RM_ROWS 32
__global__ __launch_bounds__(256) void k_rowmat_tile(
    const bf16* __restrict__ in, const float* __restrict__ W,
    const float* __restrict__ bias, bf16* __restrict__ outv)
{
    __shared__ float wlds[128*129];
    __shared__ float rlds[RM_ROWS][128];
    int tid = threadIdx.x;
    size_t row0 = (size_t)blockIdx.x * RM_ROWS;
    for (int idx = tid; idx < 16384; idx += 256)
        wlds[(idx >> 7)*129 + (idx & 127)] = W[idx];
    for (int idx = tid; idx < RM_ROWS*128; idx += 256)
        rlds[idx >> 7][idx & 127] = b2f(in[row0*128 + idx]);
    __syncthreads();
    int l = tid & 127, g = tid >> 7;
    float bl = bias[l];
    #pragma unroll
    for (int rg = 0; rg < 16; rg += 4) {
        int r0 = 2*rg + g;                 // rows r0, r0+2, r0+4, r0+6
        float a0=0.f, a1=0.f, a2=0.f, a3=0.f;
        for (int k = 0; k < 128; ++k) {
            float w = wlds[l*129 + k];
            a0 += rlds[r0][k]*w;   a1 += rlds[r0+2][k]*w;
            a2 += rlds[r0+4][k]*w; a3 += rlds[r0+6][k]*w;
        }
        outv[(row0 + r0  )*128 + l] = f2b(lrelu(a0+bl));
        outv[(row0 + r0+2)*128 + l] = f2b(lrelu(a1+bl));
        outv[(row0 + r0+4)*128 + l] = f2b(lrelu(a2+bl));
        outv[(row0 + r0+6)*128 + l] = f2b(lrelu(a3+bl));
    }
}

// ---------------------------------------------------------------------------
// Tiled masked att-pool: v[r][l] = lrelu(in[r][:] . W[l][:] + b[l]) * mask[r];
// per-block partial sums, ONE atomicAdd per l per block.
__global__ __launch_bounds__(256) void k_att_acc_tile(
    const bf16* __restrict__ in, const float* __restrict__ W,
    const float* __restrict__ bias, const float* __restrict__ mask,
    float* __restrict__ acc, int per_b)
{
    __shared__ float wlds[128*129];
    __shared__ float rlds[RM_ROWS][128];
    __shared__ float mlds[RM_ROWS];
    __shared__ float psum[128];
    int tid = threadIdx.x;
    size_t row0 = (size_t)blockIdx.x * RM_ROWS;
    int b = (int)(row0 / per_b);           // RM_ROWS | per_b -> tile within one b
    for (int idx = tid; idx < 16384; idx += 256)
        wlds[(idx >> 7)*129 + (idx & 127)] = W[idx];
    for (int idx = tid; idx < RM_ROWS*128; idx += 256)
        rlds[idx >> 7][idx & 127] = b2f(in[row0*128 + idx]);
    if (tid < RM_ROWS) mlds[tid] = mask[row0 + tid];
    __syncthreads();
    int l = tid & 127, g = tid >> 7;
    float bl = bias[l];
    float vsum = 0.f;
    #pragma unroll
    for (int rg = 0; rg < 16; rg += 4) {
        int r0 = 2*rg + g;
        float a0=0.f, a1=0.f, a2=0.f, a3=0.f;
        for (int k = 0; k < 128; ++k) {
            float w = wlds[l*129 + k];
            a0 += rlds[r0][k]*w;   a1 += rlds[r0+2][k]*w;
            a2 += rlds[r0+4][k]*w; a3 += rlds[r0+6][k]*w;
        }
        vsum += lrelu(a0+bl)*mlds[r0]   + lrelu(a1+bl)*mlds[r0+2]
              + lrelu(a2+bl)*mlds[r0+4] + lrelu(a3+bl)*mlds[r0+6];
    }
    if (g == 1) psum[l] = vsum;
    __syncthreads();
    if (g == 0) atomicAdd(&acc[b*128 + l], vsum + psum[l]);
}

// ---------------------------------------------------------------------------
// 11x11 SAME conv over (1024,128) + relu. layer 0 gathers E_amino from params.
__global__ __launch_bounds__(128) void k_conv(
    const bf16* __restrict__ in, const int* __restrict__ amino,
    const float* __restrict__ params, bf16* __restrict__ out,
    int layer, int first)
{
    int bid = blockIdx.x;              // b*1024 + i
    int b = bid >> 10, i = bid & 1023;
    int tid = threadIdx.x;
    __shared__ float tile[11][139];
    __shared__ float wts[121];
    __shared__ float bias;
    if (tid < 121) wts[tid] = params[P_CONV_W + layer*121 + tid];
    if (tid == 121) bias = params[P_CONV_B + layer];
    for (int idx = tid; idx < 11*138; idx += 128) {
        int r = idx / 138, cc = idx % 138;
        int ri = i + r - 5, cj = cc - 5;
        float v = 0.f;
        if (ri >= 0 && ri < 1024 && cj >= 0 && cj < 128) {
            v = first ? params[P_E_AMINO + amino[b*1024 + ri]*128 + cj]
                      : b2f(in[((size_t)(b*1024 + ri))*128 + cj]);
        }
        tile[r][cc] = v;
    }
    __syncthreads();
    float a = bias;
    #pragma unroll
    for (int di = 0; di < 11; ++di)
        #pragma unroll
        for (int dj = 0; dj < 11; ++dj)
            a += tile[di][tid + dj] * wts[di*11 + dj];
    out[(size_t)bid*128 + tid] = f2b(fmaxf(a, 0.f));
}

// ---------------------------------------------------------------------------
// final: mask means, leaky x2, pred dot.  block per b.  OUTPUT IS FLOAT32.
__global__ __launch_bounds__(256) void k_final(
    const float* __restrict__ params, const float* __restrict__ acc,
    float* __restrict__ out)
{
    int b = blockIdx.x, tid = threadIdx.x;
    __shared__ float red[256];
    float s = 0.f;
    for (int t = tid; t < 512; t += 256) s += params[P_ATOMS_MASK + b*512 + t];
    #pragma unroll
    for (int m = 32; m; m >>= 1) s += __shfl_xor(s, m, 64);
    if ((tid & 63) == 0) red[tid >> 6] = s;
    __syncthreads();
    float sum_atoms = red[0]+red[1]+red[2]+red[3];
    __syncthreads();
    s = 0.f;
    for (int t = tid; t < 1024; t += 256) s += params[P_AMINO_MASK + b*1024 + t];
    #pragma unroll
    for (int m = 32; m; m >>= 1) s += __shfl_xor(s, m, 64);
    if ((tid & 63) == 0) red[tid >> 6] = s;
    __syncthreads();
    float sum_amino = red[0]+red[1]+red[2]+red[3];
    __syncthreads();
    float val = (tid < 128) ? acc[b*128 + tid] / sum_atoms
                            : acc[2048 + b*128 + (tid-128)] / sum_amino;
    val = lrelu(lrelu(val));
    val *= params[P_PRED_W + tid];
    #pragma unroll
    for (int m = 32; m; m >>= 1) val += __shfl_xor(val, m, 64);
    if ((tid & 63) == 0) red[tid >> 6] = val;
    __syncthreads();
    if (tid == 0) out[b] = red[0]+red[1]+red[2]+red[3] + params[P_PRED_B];
}

// ---------------------------------------------------------------------------
extern "C" void kernel_launch(void* const* d_in, const int* in_sizes, int n_in,
                              void* d_out, int out_size, void* d_ws, size_t ws_size,
                              hipStream_t stream)
{
    const int* atoms     = (const int*)d_in[0];
    const int* adjacency = (const int*)d_in[2];
    const int* amino     = (const int*)d_in[3];
    float* out = (float*)d_out;                  // reference output dtype = f32
    (void)in_sizes; (void)n_in; (void)ws_size;

    // ws layout: total ~12.9 MiB
    char* base = (char*)d_ws;
    float* params = (float*)(base + 0);          // 141167 f32 (565 KB)
    float* src1   = (float*)(base + 565248);     // 32768 f32
    float* dst1   = (float*)(base + 696320);     // 32768 f32
    float* src2   = (float*)(base + 827392);     // 8192 f32
    float* dst2   = (float*)(base + 860160);     // 8192 f32
    float* acc    = (float*)(base + 892928);     // 4096 f32 (comp | prot)
    bf16*  A      = (bf16*)(base + 909568);      // 2,097,152 bf16
    bf16*  B      = (bf16*)(base + 5103872);     // 2,097,152 bf16
    bf16*  C      = (bf16*)(base + 9298176);     // 2,097,152 bf16

    bf16* Wh1 = B;
    bf16* multi = C;
    bf16* Wh2 = B;                 // first 1,048,576 elems (Wh1 dead)
    bf16* xbuf = B + 1048576;      // second 1,048,576 elems
    bf16* atoms_vec = C;           // multi dead

    hipMemsetAsync(acc, 0, 4096*sizeof(float), stream);

    // per-tensor conversions (small kernargs)
    k_cvt<<< 32, 256, 0, stream>>>(d_in[1],  params + P_ATOMS_MASK, 8192);
    k_cvt<<< 64, 256, 0, stream>>>(d_in[4],  params + P_AMINO_MASK, 16384);
    k_cvt<<< 50, 256, 0, stream>>>(d_in[5],  params + P_E_ATOM,     12800);
    k_cvt<<< 15, 256, 0, stream>>>(d_in[6],  params + P_E_AMINO,    3840);
    k_cvt<<<128, 256, 0, stream>>>(d_in[7],  params + P_W_GAT,      32768);
    k_cvt<<<  2, 256, 0, stream>>>(d_in[8],  params + P_A_GAT,      512);
    k_cvt<<<128, 256, 0, stream>>>(d_in[9],  params + P_W_GO,       32768);
    k_cvt<<<  1, 256, 0, stream>>>(d_in[10], params + P_A_GO,       256);
    k_cvt<<< 64, 256, 0, stream>>>(d_in[11], params + P_W_COMP_W,   16384);
    k_cvt<<<  1, 256, 0, stream>>>(d_in[12], params + P_W_COMP_B,   128);
    k_cvt<<<  2, 256, 0, stream>>>(d_in[13], params + P_CONV_W,     363);
    k_cvt<<<  1, 256, 0, stream>>>(d_in[14], params + P_CONV_B,     3);
    k_cvt<<< 64, 256, 0, stream>>>(d_in[15], params + P_W_ATT_W,    16384);
    k_cvt<<<  1, 256, 0, stream>>>(d_in[16], params + P_W_ATT_B,    128);
    k_cvt<<<  1, 256, 0, stream>>>(d_in[17], params + P_PRED_W,     256);
    k_cvt<<<  1, 256, 0, stream>>>(d_in[18], params + P_PRED_B,     1);

    // protein conv chain
    k_conv<<<16384, 128, 0, stream>>>(nullptr, amino, params, A, 0, 1);
    k_conv<<<16384, 128, 0, stream>>>(A,       amino, params, B, 1, 0);
    k_conv<<<16384, 128, 0, stream>>>(B,       amino, params, A, 2, 0);   // A = amino_vec

    // GAT layer 1 (4 heads, merged per block)
    k_gat1_pre<<<8192, 256, 0, stream>>>(atoms, params, Wh1, src1, dst1);
    k_gat1_att4<<<8192, 256, 0, stream>>>(adjacency, Wh1, src1, dst1, multi);

    // GAT layer 2
    k_gat2_pre<<<8192, 128, 0, stream>>>(multi, params, Wh2, src2, dst2);
    k_gat2_att<<<8192, 256, 0, stream>>>(adjacency, Wh2, src2, dst2, xbuf);

    // atoms_vec = leaky(x @ W_comp^T + b)   (tiled, W in LDS)
    k_rowmat_tile<<<256, 256, 0, stream>>>(xbuf, params + P_W_COMP_W,
                                           params + P_W_COMP_B, atoms_vec);

    // masked attention-pool accumulations (tiled, W in LDS)
    k_att_acc_tile<<<256, 256, 0, stream>>>(atoms_vec, params + P_W_ATT_W,
                                            params + P_W_ATT_B, params + P_ATOMS_MASK,
                                            acc, 512);
    k_att_acc_tile<<<512, 256, 0, stream>>>(A, params + P_W_ATT_W,
                                            params + P_W_ATT_B, params + P_AMINO_MASK,
                                            acc + 2048, 1024);

    // head (float32 output)
    k_final<<<16, 256, 0, stream>>>(params, acc, out);
}